// Round 2
// baseline (66.833 us; speedup 1.0000x reference)
//
#include <hip/hip_runtime.h>
#include <hip/hip_bf16.h>

#define KCOLS 262144
#define LAT 64
#define HID 40

// ---------------------------------------------------------------------------
// Kernel 1: transpose the six weight matrices into d_ws so the main kernel's
// inner (unrolled) loops read CONSECUTIVE uniform addresses -> s_load_dwordxN.
// Layout in ws (floats):
//   [0,2560)      W1oT[r*40+j] = W_o1[j*64+r]   (64x40)
//   [2560,5120)   W1tT[r*40+j] = W_t1[j*64+r]
//   [5120,6720)   W2oT[r*40+j] = W_o2[j*40+r]   (40x40)
//   [6720,8320)   W2tT[r*40+j] = W_t2[j*40+r]
//   [8320,8680)   W3oT[r*9+j]  = W_o3[j*40+r]   (40x9)
//   [8680,8800)   W3tT[r*3+j]  = W_t3[j*40+r]   (40x3)
// ---------------------------------------------------------------------------
__global__ __launch_bounds__(256) void transpose_w(
    const float* __restrict__ Wo1, const float* __restrict__ Wt1,
    const float* __restrict__ Wo2, const float* __restrict__ Wt2,
    const float* __restrict__ Wo3, const float* __restrict__ Wt3,
    float* __restrict__ ws)
{
    int t = blockIdx.x * blockDim.x + threadIdx.x;
    if (t < 2560) {
        int r = t / 40, j = t % 40;
        ws[t]        = Wo1[j * 64 + r];
        ws[2560 + t] = Wt1[j * 64 + r];
    }
    if (t < 1600) {
        int r = t / 40, j = t % 40;
        ws[5120 + t] = Wo2[j * 40 + r];
        ws[6720 + t] = Wt2[j * 40 + r];
    }
    if (t < 360) {
        int r = t / 9, j = t % 9;
        ws[8320 + t] = Wo3[j * 40 + r];
    }
    if (t < 120) {
        int r = t / 3, j = t % 3;
        ws[8680 + t] = Wt3[j * 40 + r];
    }
}

// ---------------------------------------------------------------------------
// Kernel 2: fused MLP (both branches) + 3x3 expm, one thread per column.
// All weight reads are wave-uniform (scalar-cache); x reads / out writes are
// fully coalesced. OUTPUT IS FLOAT32 (reference output dtype).
// ---------------------------------------------------------------------------
__global__ __launch_bounds__(256) void fused_main(
    const float* __restrict__ x,
    const float* __restrict__ ws,
    const float* __restrict__ bo1, const float* __restrict__ bo2,
    const float* __restrict__ bo3, const float* __restrict__ bt1,
    const float* __restrict__ bt2, const float* __restrict__ bt3,
    float* __restrict__ out)
{
    const int k = blockIdx.x * blockDim.x + threadIdx.x;  // column index

    const float* W1o = ws;
    const float* W1t = ws + 2560;
    const float* W2o = ws + 5120;
    const float* W2t = ws + 6720;
    const float* W3o = ws + 8320;
    const float* W3t = ws + 8680;

    // ---- layer 1, both branches, streaming x ----
    float ho[HID], ht[HID];
#pragma unroll
    for (int j = 0; j < HID; ++j) { ho[j] = bo1[j]; ht[j] = bt1[j]; }

    for (int r = 0; r < LAT; ++r) {
        float xv = x[(size_t)r * KCOLS + k];
        const float* wo = W1o + r * HID;
        const float* wt = W1t + r * HID;
#pragma unroll
        for (int j = 0; j < HID; ++j) {
            ho[j] = fmaf(wo[j], xv, ho[j]);
            ht[j] = fmaf(wt[j], xv, ht[j]);
        }
    }
#pragma unroll
    for (int j = 0; j < HID; ++j) {
        ho[j] = fmaxf(ho[j], 0.0f);
        ht[j] = fmaxf(ht[j], 0.0f);
    }

    // ---- omega branch: layer 2 ----
    float g[HID];
#pragma unroll
    for (int j = 0; j < HID; ++j) g[j] = bo2[j];
    for (int r = 0; r < HID; ++r) {
        float hv = ho[r];
        const float* w = W2o + r * HID;
#pragma unroll
        for (int j = 0; j < HID; ++j) g[j] = fmaf(w[j], hv, g[j]);
    }

    // ---- omega branch: layer 3 (relu fused on input) ----
    float om[9];
#pragma unroll
    for (int j = 0; j < 9; ++j) om[j] = bo3[j];
    for (int r = 0; r < HID; ++r) {
        float hv = fmaxf(g[r], 0.0f);
        const float* w = W3o + r * 9;
#pragma unroll
        for (int j = 0; j < 9; ++j) om[j] = fmaf(w[j], hv, om[j]);
    }
#pragma unroll
    for (int j = 0; j < 9; ++j) om[j] = fmaxf(om[j], 0.0f);

    // write omega (rows 0..8) as f32
#pragma unroll
    for (int j = 0; j < 9; ++j)
        out[(size_t)j * KCOLS + k] = om[j];

    // ---- expm(omega as 3x3 row-major), scaling(1/32) + Taylor-9 + 5 squarings
    float B[9];
#pragma unroll
    for (int i = 0; i < 9; ++i) B[i] = om[i] * (1.0f / 32.0f);

    float T[9] = {1.f, 0.f, 0.f, 0.f, 1.f, 0.f, 0.f, 0.f, 1.f};
#pragma unroll
    for (int m = 9; m >= 1; --m) {
        float U[9];
#pragma unroll
        for (int rr = 0; rr < 3; ++rr) {
#pragma unroll
            for (int cc = 0; cc < 3; ++cc) {
                U[rr * 3 + cc] = B[rr * 3 + 0] * T[0 * 3 + cc]
                               + B[rr * 3 + 1] * T[1 * 3 + cc]
                               + B[rr * 3 + 2] * T[2 * 3 + cc];
            }
        }
        const float s = 1.0f / (float)m;
#pragma unroll
        for (int i = 0; i < 9; ++i)
            T[i] = U[i] * s + ((i == 0 || i == 4 || i == 8) ? 1.0f : 0.0f);
    }
#pragma unroll
    for (int q = 0; q < 5; ++q) {
        float U[9];
#pragma unroll
        for (int rr = 0; rr < 3; ++rr) {
#pragma unroll
            for (int cc = 0; cc < 3; ++cc) {
                U[rr * 3 + cc] = T[rr * 3 + 0] * T[0 * 3 + cc]
                               + T[rr * 3 + 1] * T[1 * 3 + cc]
                               + T[rr * 3 + 2] * T[2 * 3 + cc];
            }
        }
#pragma unroll
        for (int i = 0; i < 9; ++i) T[i] = U[i];
    }

    // write rotation (rows 9..17) as f32
#pragma unroll
    for (int j = 0; j < 9; ++j)
        out[(size_t)(9 + j) * KCOLS + k] = T[j];

    // ---- translation branch: layer 2 (reuse g) ----
#pragma unroll
    for (int j = 0; j < HID; ++j) g[j] = bt2[j];
    for (int r = 0; r < HID; ++r) {
        float hv = ht[r];
        const float* w = W2t + r * HID;
#pragma unroll
        for (int j = 0; j < HID; ++j) g[j] = fmaf(w[j], hv, g[j]);
    }

    // ---- translation branch: layer 3 ----
    float tr[3];
#pragma unroll
    for (int j = 0; j < 3; ++j) tr[j] = bt3[j];
    for (int r = 0; r < HID; ++r) {
        float hv = fmaxf(g[r], 0.0f);
        const float* w = W3t + r * 3;
#pragma unroll
        for (int j = 0; j < 3; ++j) tr[j] = fmaf(w[j], hv, tr[j]);
    }
#pragma unroll
    for (int j = 0; j < 3; ++j)
        out[(size_t)(18 + j) * KCOLS + k] = fmaxf(tr[j], 0.0f);
}

extern "C" void kernel_launch(void* const* d_in, const int* in_sizes, int n_in,
                              void* d_out, int out_size, void* d_ws, size_t ws_size,
                              hipStream_t stream) {
    const float* x   = (const float*)d_in[0];
    const float* Wo1 = (const float*)d_in[1];
    const float* bo1 = (const float*)d_in[2];
    const float* Wo2 = (const float*)d_in[3];
    const float* bo2 = (const float*)d_in[4];
    const float* Wo3 = (const float*)d_in[5];
    const float* bo3 = (const float*)d_in[6];
    const float* Wt1 = (const float*)d_in[7];
    const float* bt1 = (const float*)d_in[8];
    const float* Wt2 = (const float*)d_in[9];
    const float* bt2 = (const float*)d_in[10];
    const float* Wt3 = (const float*)d_in[11];
    const float* bt3 = (const float*)d_in[12];

    float* ws = (float*)d_ws;
    float* out = (float*)d_out;

    hipLaunchKernelGGL(transpose_w, dim3(10), dim3(256), 0, stream,
                       Wo1, Wt1, Wo2, Wt2, Wo3, Wt3, ws);
    hipLaunchKernelGGL(fused_main, dim3(KCOLS / 256), dim3(256), 0, stream,
                       x, ws, bo1, bo2, bo3, bt1, bt2, bt3, out);
}